// Round 3
// baseline (689.418 us; speedup 1.0000x reference)
//
#include <hip/hip_runtime.h>

// ---------------------------------------------------------------------------
// DenseGATLayer: LN1 -> fused QKV proj -> adj-masked MHA -> WO proj + residual
//                -> LN2 -> GELU FFN -> residual
// B=32 N=512 D=768 H=12 HD=64. bf16 MFMA, fp32 accumulation.
// R6: double-buffered single-barrier GEMM K-loop, 128x128 tiles, fused QKV.
// R7: parallel sniff_k (was 120us serial-latency).
// R8: attn was top (111us, VALUBusy 57% vs MfmaUtil 9.7% = VALU-bound +
// exposed staging latency). Now: T14 reg-staged K/V prefetch (latency hides
// under compute), Q frags in regs (LDS 36->27.6KB, 4->5 blocks/CU), deferred
// l_i cross-lane reduction (saves 128 shfl/lane), exp2-domain softmax,
// s_setprio around MFMA clusters.
// ---------------------------------------------------------------------------

#define Bn 32
#define Nn 512
#define Dn 768
#define Hn 12
#define HDn 64
#define Mn (Bn * Nn)      // 16384 rows
#define DFn 3072          // FFN hidden
#define MCHUNK 8192       // FFN M-chunk rows (hidden = 50.3 MB -> Rq+Rk)

typedef unsigned short u16;
typedef unsigned long long u64;
typedef short bf16x8 __attribute__((ext_vector_type(8)));
typedef float f32x4 __attribute__((ext_vector_type(4)));
typedef unsigned short u16x8 __attribute__((ext_vector_type(8)));

__device__ __forceinline__ float b2f(u16 u) {
    return __uint_as_float(((unsigned int)u) << 16);
}
__device__ __forceinline__ u16 f2b(float f) {
    unsigned int u = __float_as_uint(f);
    u += 0x7fffu + ((u >> 16) & 1u);   // RNE
    return (u16)(u >> 16);
}
__device__ __forceinline__ float loadDyn(const void* p, size_t i, int f) {
    return f ? ((const float*)p)[i] : b2f(((const u16*)p)[i]);
}
__device__ __forceinline__ float gelu_exact(float x) {
    return 0.5f * x * (1.0f + erff(x * 0.70710678118654752f));
}

// async global->LDS, 16B/lane; LDS dest = wave-uniform base + lane*16.
__device__ __forceinline__ void gl_lds16(const u16* g, u16* l) {
    __builtin_amdgcn_global_load_lds(
        (const __attribute__((address_space(1))) void*)(unsigned long long)(const void*)g,
        (__attribute__((address_space(3))) void*)(unsigned)(unsigned long long)(void*)l,
        16, 0, 0);
}

// ---------------------------------------------------------------------------
// Dtype sniffer (bf16 vs fp32 inputs). Parallel: 64 blocks x 256 threads x
// u16x8, wave-reduce, one atomicAdd per wave. flag pre-zeroed by
// hipMemsetAsync; consumers treat f = (*flag > 32).
// ---------------------------------------------------------------------------
__global__ __launch_bounds__(256) void sniff_k(const u16* __restrict__ x,
                                               int* __restrict__ flag) {
    const int idx = blockIdx.x * 256 + threadIdx.x;
    u16x8 a = *(const u16x8*)&x[(size_t)idx * 8];
    int cnt = 0;
#pragma unroll
    for (int e = 0; e < 8; e++)
        cnt += ((a[e] & 0x7F80) == 0x7F80) ? 1 : 0;
#pragma unroll
    for (int off = 1; off <= 32; off <<= 1) cnt += __shfl_xor(cnt, off, 64);
    if ((threadIdx.x & 63) == 0 && cnt > 0) atomicAdd(flag, cnt);
}

__device__ __forceinline__ int flagval(const int* flagp) {
    return (*flagp > 32) ? 1 : 0;
}

// ---------------------------------------------------------------------------
// Pack all bias vectors to fp32: [bq 768 | bk 768 | bv 768 | bo 768 |
// bf1 3072 | bf2 768] = 6912 floats.
// ---------------------------------------------------------------------------
__global__ __launch_bounds__(256) void pack_bias_k(
    const void* __restrict__ bq, const void* __restrict__ bk,
    const void* __restrict__ bv, const void* __restrict__ bo,
    const void* __restrict__ bf1, const void* __restrict__ bf2,
    float* __restrict__ out, const int* __restrict__ flagp) {
    const int f = flagval(flagp);
    const int i = blockIdx.x * 256 + threadIdx.x;
    if (i >= 6912) return;
    const void* src;
    int off;
    if (i < 768)       { src = bq;  off = i; }
    else if (i < 1536) { src = bk;  off = i - 768; }
    else if (i < 2304) { src = bv;  off = i - 1536; }
    else if (i < 3072) { src = bo;  off = i - 2304; }
    else if (i < 6144) { src = bf1; off = i - 3072; }
    else               { src = bf2; off = i - 6144; }
    out[i] = loadDyn(src, off, f);
}

// ---------------------------------------------------------------------------
// adj -> bitmask: mask[row*8 + seg] bit j = (adj[row][seg*64+j] != 0).
// ---------------------------------------------------------------------------
__global__ __launch_bounds__(256) void mask_build_k(
    const int* __restrict__ adj, u64* __restrict__ mask) {
    const int idx = blockIdx.x * 256 + threadIdx.x;   // Mn*8 = 131072 ids
    const size_t base = (size_t)(idx >> 3) * Nn + (size_t)(idx & 7) * 64;
    const int4* p = (const int4*)(adj + base);
    u64 m = 0;
#pragma unroll
    for (int c = 0; c < 16; c++) {
        int4 a = p[c];
        if (a.x) m |= 1ull << (c * 4 + 0);
        if (a.y) m |= 1ull << (c * 4 + 1);
        if (a.z) m |= 1ull << (c * 4 + 2);
        if (a.w) m |= 1ull << (c * 4 + 3);
    }
    mask[idx] = m;
}

// ---------------------------------------------------------------------------
// Transpose raw weight -> canonical bf16: out[c][r] = in[r][c]
// ---------------------------------------------------------------------------
__global__ __launch_bounds__(256) void transpose_k(
    const void* __restrict__ in, u16* __restrict__ out, int R, int C,
    const int* __restrict__ flagp) {
    const int f = flagval(flagp);
    __shared__ u16 tile[32][33];
    int c0 = blockIdx.x * 32, r0 = blockIdx.y * 32;
    int tx = threadIdx.x, ty = threadIdx.y;  // 32 x 8
#pragma unroll
    for (int i = 0; i < 32; i += 8)
        tile[ty + i][tx] = f2b(loadDyn(in, (size_t)(r0 + ty + i) * C + c0 + tx, f));
    __syncthreads();
#pragma unroll
    for (int i = 0; i < 32; i += 8)
        out[(size_t)(c0 + ty + i) * R + r0 + tx] = tile[tx][ty + i];
}

// ---------------------------------------------------------------------------
// V [b][n][h][d] -> Vt [b*H+h][d][n]
// ---------------------------------------------------------------------------
__global__ __launch_bounds__(256) void vtrans_k(
    const u16* __restrict__ v, u16* __restrict__ vt) {
    __shared__ u16 tile[32][33];
    const int bh = blockIdx.z;                 // b*Hn + h
    const int d0 = blockIdx.x * 32;            // 0 / 32
    const int n0 = blockIdx.y * 32;
    const int b = bh / Hn, h = bh % Hn;
    const int tx = threadIdx.x, ty = threadIdx.y;   // 32 x 8
#pragma unroll
    for (int i = 0; i < 32; i += 8)
        tile[ty + i][tx] =
            v[(size_t)(b * Nn + n0 + ty + i) * Dn + h * HDn + d0 + tx];
    __syncthreads();
#pragma unroll
    for (int i = 0; i < 32; i += 8)
        vt[((size_t)bh * HDn + d0 + ty + i) * Nn + n0 + tx] = tile[tx][ty + i];
}

// ---------------------------------------------------------------------------
// LayerNorm over D=768. 8 rows/block, 32 lanes/row, u16x8 vector loads.
// ---------------------------------------------------------------------------
template <int XDYN>
__global__ __launch_bounds__(256) void ln_k(
    const void* __restrict__ x, const void* __restrict__ g,
    const void* __restrict__ b, u16* __restrict__ y,
    const int* __restrict__ flagp) {
    const int f = flagval(flagp);
    const int t = threadIdx.x;
    const int row = blockIdx.x * 8 + (t >> 5);
    const int l32 = t & 31;
    const size_t base = (size_t)row * Dn;
    float v[24];
    if (XDYN == 0 || f == 0) {   // bf16 path (ws buffers always bf16)
        const u16* xp = (const u16*)x;
#pragma unroll
        for (int kk = 0; kk < 3; kk++) {
            u16x8 a = *(const u16x8*)&xp[base + kk * 256 + l32 * 8];
#pragma unroll
            for (int e = 0; e < 8; e++) v[kk * 8 + e] = b2f(a[e]);
        }
    } else {
#pragma unroll
        for (int kk = 0; kk < 3; kk++)
#pragma unroll
            for (int e = 0; e < 8; e++)
                v[kk * 8 + e] = loadDyn(x, base + kk * 256 + l32 * 8 + e, f);
    }
    float s = 0.f;
#pragma unroll
    for (int i = 0; i < 24; i++) s += v[i];
#pragma unroll
    for (int off = 1; off <= 16; off <<= 1) s += __shfl_xor(s, off, 64);
    const float mu = s * (1.0f / Dn);
    float d2 = 0.f;
#pragma unroll
    for (int i = 0; i < 24; i++) { float d = v[i] - mu; d2 += d * d; }
#pragma unroll
    for (int off = 1; off <= 16; off <<= 1) d2 += __shfl_xor(d2, off, 64);
    const float rstd = rsqrtf(d2 * (1.0f / Dn) + 1e-5f);
#pragma unroll
    for (int kk = 0; kk < 3; kk++) {
        const int c0 = kk * 256 + l32 * 8;
        u16x8 o;
        if (f == 0) {
            u16x8 gv = *(const u16x8*)&((const u16*)g)[c0];
            u16x8 bv = *(const u16x8*)&((const u16*)b)[c0];
#pragma unroll
            for (int e = 0; e < 8; e++)
                o[e] = f2b((v[kk * 8 + e] - mu) * rstd * b2f(gv[e]) + b2f(bv[e]));
        } else {
#pragma unroll
            for (int e = 0; e < 8; e++)
                o[e] = f2b((v[kk * 8 + e] - mu) * rstd * loadDyn(g, c0 + e, f)
                           + loadDyn(b, c0 + e, f));
        }
        *(u16x8*)&y[base + c0] = o;
    }
}

// ---------------------------------------------------------------------------
// GEMM: C[moff+M][N] = epi( A[M][K] @ Bt[N][K]^T + bias (+res) ).
// Block tile 128 x (2*WN), BK=32, 4 waves (2x2); wave tile 64 x WN.
// Double-buffered LDS, ONE barrier per K-step (stage-next-then-compute).
// CSPLIT>0: output columns routed in CSPLIT-wide regions to consecutive
// [M][CSPLIT] buffers (fused QKV -> contiguous Rq/Rk/Rv).
// ---------------------------------------------------------------------------
template <int ACT, int RES, int STORE, int WN, int CSPLIT>
__global__ __launch_bounds__(256, 3) void gemm_bt(
    const u16* __restrict__ A, const u16* __restrict__ Bt,
    const float* __restrict__ bias, const void* __restrict__ res,
    void* __restrict__ C, int M, int N, int K, int moff,
    const int* __restrict__ flagp) {
    constexpr int BN = 2 * WN;
    constexpr int NJ = WN / 16;       // B-fragments per wave
    constexpr int NB = BN / 64;       // B staging chunks per thread
    const int f = flagval(flagp);
    __shared__ __align__(16) u16 As[2][128 * 32];
    __shared__ __align__(16) u16 Bs[2][BN * 32];
    const int tid = threadIdx.x;
    const int m0 = blockIdx.x * 128, n0 = blockIdx.y * BN;
    const int wave = tid >> 6, lane = tid & 63;
    const int wm = (wave & 1) * 64, wn = (wave >> 1) * WN;
    const int lm = lane & 15, quad = lane >> 4;

    const int koff = (tid & 3) * 8;
    const int srow = tid >> 2;                       // 0..63
    const u16* gA[2];
    const u16* gB[NB];
#pragma unroll
    for (int i = 0; i < 2; i++)
        gA[i] = A + (size_t)(m0 + srow + i * 64) * K + koff;
#pragma unroll
    for (int i = 0; i < NB; i++)
        gB[i] = Bt + (size_t)(n0 + srow + i * 64) * K + koff;

    f32x4 acc[4][NJ] = {};

    auto stage = [&](int buf) {
#pragma unroll
        for (int i = 0; i < 2; i++) {
            gl_lds16(gA[i], &As[buf][(tid + i * 256) * 8]);
            gA[i] += 32;
        }
#pragma unroll
        for (int i = 0; i < NB; i++) {
            gl_lds16(gB[i], &Bs[buf][(tid + i * 256) * 8]);
            gB[i] += 32;
        }
    };
    auto compute = [&](int buf) {
        bf16x8 af[4], bfv[NJ];
#pragma unroll
        for (int i = 0; i < 4; i++)
            af[i] = *(const bf16x8*)&As[buf][(wm + i * 16 + lm) * 32 + quad * 8];
#pragma unroll
        for (int j = 0; j < NJ; j++)
            bfv[j] = *(const bf16x8*)&Bs[buf][(wn + j * 16 + lm) * 32 + quad * 8];
#pragma unroll
        for (int i = 0; i < 4; i++)
#pragma unroll
            for (int j = 0; j < NJ; j++)
                acc[i][j] = __builtin_amdgcn_mfma_f32_16x16x32_bf16(
                    af[i], bfv[j], acc[i][j], 0, 0, 0);
    };

    stage(0);                          // prologue: tile 0 in flight
    int cur = 0;
    for (int k0 = 32; k0 < K; k0 += 32) {
        __syncthreads();               // drains vmcnt: buf[cur] ready; prior
                                       // readers of buf[cur^1] are done
        stage(cur ^ 1);                // next tile flies during compute
        compute(cur);
        cur ^= 1;
    }
    __syncthreads();
    compute(cur);                      // epilogue tile (no prefetch)

    float bias_f[NJ];
#pragma unroll
    for (int j = 0; j < NJ; j++)
        bias_f[j] = bias[n0 + wn + j * 16 + lm];
#pragma unroll
    for (int i = 0; i < 4; i++) {
#pragma unroll
        for (int r = 0; r < 4; r++) {
            const int row = m0 + wm + i * 16 + quad * 4 + r;  // C/D: row=quad*4+reg
#pragma unroll
            for (int j = 0; j < NJ; j++) {
                int col = n0 + wn + j * 16 + lm;              // C/D: col=lane&15
                size_t rb;
                if (CSPLIT > 0) {
                    const int reg = col / CSPLIT;             // const div
                    rb = ((size_t)reg * M + moff + row) * (size_t)CSPLIT;
                    col -= reg * CSPLIT;
                } else {
                    rb = (size_t)(moff + row) * N;
                }
                float vv = acc[i][j][r] + bias_f[j];
                if (ACT == 1) vv = gelu_exact(vv);
                if (RES == 1) vv += b2f(((const u16*)res)[rb + col]);
                if (RES == 2) vv += loadDyn(res, rb + col, f);
                if (STORE == 0) ((u16*)C)[rb + col] = f2b(vv);
                else {
                    if (f) ((float*)C)[rb + col] = vv;
                    else   ((u16*)C)[rb + col] = f2b(vv);
                }
            }
        }
    }
}

// ---------------------------------------------------------------------------
// MFMA masked flash-attention. Block = (h, q-tile 64, b), 4 waves; wave w
// owns query rows w*16..+16. Q frags in regs (loop-invariant); K/Vt tiles
// reg-prefetched one iteration ahead (T14: global latency hides under
// compute); exp2-domain online softmax with per-lane deferred l-reduction;
// s_setprio(1) around MFMA clusters. o may alias q (disjoint rows/cols).
// ---------------------------------------------------------------------------
__global__ __launch_bounds__(256) void attn_mfma_k(
    const u16* q, const u16* __restrict__ k,
    const u16* __restrict__ vt, const u64* __restrict__ mask, u16* o) {
    const int h = blockIdx.x, qg = blockIdx.y, b = blockIdx.z;
    const int q0 = qg * 64;
    const int tid = threadIdx.x;
    const int wave = tid >> 6, lane = tid & 63;
    const int lm = lane & 15, quad = lane >> 4;
    const int wm = wave * 16;
    const int bh = b * Hn + h;
    const float SC2 = 0.125f * 1.4426950408889634f;   // scale * log2(e)

    __shared__ __align__(16) u16 Ks[64 * 72];
    __shared__ __align__(16) u16 Vts[64 * 72];   // [dim][key]
    __shared__ __align__(16) u16 Ps[64 * 72];

    // Q fragments direct from global (constant across k-tiles)
    const u16* qrow = q + ((size_t)(b * Nn + q0 + wm + lm)) * Dn + h * HDn + quad * 8;
    const bf16x8 aq0 = *(const bf16x8*)(qrow);
    const bf16x8 aq1 = *(const bf16x8*)(qrow + 32);

    // staging addresses: thread stages K row srow / Vt dim srow, 32B chunk
    const int srow = tid >> 2, scc = (tid & 3) * 16;
    const u16* kbase = k + ((size_t)(b * Nn + srow)) * Dn + h * HDn + scc;
    const u16* vbase = vt + ((size_t)bh * HDn + srow) * Nn + scc;

    // prologue prefetch: tile kb=0 into regs
    u16x8 kr0 = *(const u16x8*)(kbase);
    u16x8 kr1 = *(const u16x8*)(kbase + 8);
    u16x8 vr0 = *(const u16x8*)(vbase);
    u16x8 vr1 = *(const u16x8*)(vbase + 8);

    float m_i[4], l_p[4];           // row = wm + quad*4 + r; l_p per-lane partial
#pragma unroll
    for (int r = 0; r < 4; r++) { m_i[r] = -3e38f; l_p[r] = 0.f; }
    f32x4 Oacc[4] = {};             // dim = j*16+lm

    for (int kb = 0; kb < Nn / 64; kb++) {
        __syncthreads();   // all waves done reading previous tile's Ks/Vts
        *(u16x8*)&Ks[srow * 72 + scc]      = kr0;
        *(u16x8*)&Ks[srow * 72 + scc + 8]  = kr1;
        *(u16x8*)&Vts[srow * 72 + scc]     = vr0;
        *(u16x8*)&Vts[srow * 72 + scc + 8] = vr1;
        __syncthreads();   // tile kb visible
        if (kb + 1 < Nn / 64) {      // T14: prefetch kb+1; latency hides below
            const u16* kn = kbase + (size_t)(kb + 1) * 64 * Dn;
            const u16* vn = vbase + (kb + 1) * 64;
            kr0 = *(const u16x8*)(kn);
            kr1 = *(const u16x8*)(kn + 8);
            vr0 = *(const u16x8*)(vn);
            vr1 = *(const u16x8*)(vn + 8);
        }
        // S = Q K^T (this wave's 16 rows x 64 keys)
        f32x4 sacc[4] = {};
        __builtin_amdgcn_s_setprio(1);
#pragma unroll
        for (int s = 0; s < 2; s++) {
            const bf16x8 aq = s == 0 ? aq0 : aq1;
#pragma unroll
            for (int j = 0; j < 4; j++) {
                bf16x8 bk = *(const bf16x8*)&Ks[(j * 16 + lm) * 72 + s * 32 + quad * 8];
                sacc[j] = __builtin_amdgcn_mfma_f32_16x16x32_bf16(aq, bk, sacc[j], 0, 0, 0);
            }
        }
        __builtin_amdgcn_s_setprio(0);
        // bitmask + scale (exp2 domain) + online update, per owned row r
        float alpha[4];
#pragma unroll
        for (int r = 0; r < 4; r++) {
            const u64 mrow = mask[(size_t)(b * Nn + q0 + wm + quad * 4 + r) * 8 + kb];
#pragma unroll
            for (int j = 0; j < 4; j++) {
                const int bit = (int)((mrow >> (j * 16 + lm)) & 1ull);
                sacc[j][r] = bit ? sacc[j][r] * SC2 : -3e38f;
            }
            float mx = fmaxf(fmaxf(sacc[0][r], sacc[1][r]),
                             fmaxf(sacc[2][r], sacc[3][r]));
            mx = fmaxf(mx, __shfl_xor(mx, 1, 64));
            mx = fmaxf(mx, __shfl_xor(mx, 2, 64));
            mx = fmaxf(mx, __shfl_xor(mx, 4, 64));
            mx = fmaxf(mx, __shfl_xor(mx, 8, 64));
            const float newm = fmaxf(m_i[r], mx);
            alpha[r] = exp2f(m_i[r] - newm);
            m_i[r] = newm;
            float s_ = 0.f;
#pragma unroll
            for (int j = 0; j < 4; j++) {
                const float sc = sacc[j][r];
                const float p = (sc > -1e30f) ? exp2f(sc - newm) : 0.f;
                sacc[j][r] = p;
                s_ += p;
            }
            l_p[r] = l_p[r] * alpha[r] + s_;   // per-lane partial; reduce at end
        }
        // P (C-layout) -> LDS (A-layout source); per-wave private rows
#pragma unroll
        for (int r = 0; r < 4; r++)
#pragma unroll
            for (int j = 0; j < 4; j++)
                Ps[(wm + quad * 4 + r) * 72 + j * 16 + lm] = f2b(sacc[j][r]);
#pragma unroll
        for (int j = 0; j < 4; j++)
#pragma unroll
            for (int r = 0; r < 4; r++) Oacc[j][r] *= alpha[r];
        // O += P V   (B from Vt[dim][key]: contiguous b128)
        __builtin_amdgcn_s_setprio(1);
#pragma unroll
        for (int s = 0; s < 2; s++) {
            bf16x8 ap = *(const bf16x8*)&Ps[(wm + lm) * 72 + s * 32 + quad * 8];
#pragma unroll
            for (int j = 0; j < 4; j++) {
                bf16x8 bv = *(const bf16x8*)&Vts[(j * 16 + lm) * 72 + s * 32 + quad * 8];
                Oacc[j] = __builtin_amdgcn_mfma_f32_16x16x32_bf16(ap, bv, Oacc[j], 0, 0, 0);
            }
        }
        __builtin_amdgcn_s_setprio(0);
    }
    // final cross-lane l reduction (over the 16 lm lanes sharing each row)
    float inv[4];
#pragma unroll
    for (int r = 0; r < 4; r++) {
        float l = l_p[r];
        l += __shfl_xor(l, 1, 64);
        l += __shfl_xor(l, 2, 64);
        l += __shfl_xor(l, 4, 64);
        l += __shfl_xor(l, 8, 64);
        inv[r] = (l > 0.f) ? 1.0f / l : 0.f;
    }
#pragma unroll
    for (int r = 0; r < 4; r++) {
        const int row = q0 + wm + quad * 4 + r;
        u16* dst = o + ((size_t)(b * Nn + row)) * Dn + h * HDn;
#pragma unroll
        for (int j = 0; j < 4; j++)
            dst[j * 16 + lm] = f2b(Oacc[j][r] * inv[r]);
    }
}

// ---------------------------------------------------------------------------
extern "C" void kernel_launch(void* const* d_in, const int* in_sizes, int n_in,
                              void* d_out, int out_size, void* d_ws,
                              size_t ws_size, hipStream_t stream) {
    const void* x   = d_in[0];
    const int* adj  = (const int*)d_in[1];
    const void* wq  = d_in[2];
    const void* bq  = d_in[3];
    const void* wk  = d_in[4];
    const void* bk  = d_in[5];
    const void* wv  = d_in[6];
    const void* bv  = d_in[7];
    const void* wo  = d_in[8];
    const void* bo  = d_in[9];
    const void* g1  = d_in[10];
    const void* b1  = d_in[11];
    const void* g2  = d_in[12];
    const void* b2  = d_in[13];
    const void* w1  = d_in[14];
    const void* bf1 = d_in[15];
    const void* w2  = d_in[16];
    const void* bf2 = d_in[17];

    // ---- workspace (~116 MiB) ----
    char* ws = (char*)d_ws;
    size_t off = 0;
    auto alloc = [&](size_t bytes) -> char* {
        char* p = ws + off;
        off += (bytes + 255) & ~(size_t)255;
        return p;
    };
    int* flag = (int*)alloc(4);
    u16* wqkvT = (u16*)alloc((size_t)3 * Dn * Dn * 2);     // [2304][768]
    u16* woT  = (u16*)alloc((size_t)Dn * Dn * 2);
    u16* w1T  = (u16*)alloc((size_t)Dn * DFn * 2);
    u16* w2T  = (u16*)alloc((size_t)Dn * DFn * 2);
    float* biasf = (float*)alloc(6912 * 4);                // packed fp32 biases
    u64* maskbuf = (u64*)alloc((size_t)Mn * 8 * 8);        // 1 MB
    const size_t S = (size_t)Mn * Dn * 2;                  // 25.17 MB (256-mult)
    u16* Rh = (u16*)alloc(S);   // LN1-h -> Vt -> LN2-h2
    u16* Rq = (u16*)alloc(S);   // Q -> attn-out -> hidden[lo]
    u16* Rk = (u16*)alloc(S);   // K -> hidden[hi]  (Rq+S == Rk: contiguous)
    u16* Rv = (u16*)alloc(S);   // V -> outb (WO out + residual)  (Rk+S == Rv)

    hipMemsetAsync(flag, 0, 4, stream);
    sniff_k<<<64, 256, 0, stream>>>((const u16*)x, flag);
    mask_build_k<<<Mn * 8 / 256, 256, 0, stream>>>(adj, maskbuf);
    pack_bias_k<<<27, 256, 0, stream>>>(bq, bk, bv, bo, bf1, bf2, biasf, flag);

    dim3 tb(32, 8);
    // fused QKV weight: rows 0..767 = wq^T, 768..1535 = wk^T, 1536..2303 = wv^T
    transpose_k<<<dim3(Dn / 32, Dn / 32), tb, 0, stream>>>(wq, wqkvT, Dn, Dn, flag);
    transpose_k<<<dim3(Dn / 32, Dn / 32), tb, 0, stream>>>(wk, wqkvT + (size_t)Dn * Dn, Dn, Dn, flag);
    transpose_k<<<dim3(Dn / 32, Dn / 32), tb, 0, stream>>>(wv, wqkvT + (size_t)2 * Dn * Dn, Dn, Dn, flag);
    transpose_k<<<dim3(Dn / 32, Dn / 32), tb, 0, stream>>>(wo, woT, Dn, Dn, flag);
    transpose_k<<<dim3(DFn / 32, Dn / 32), tb, 0, stream>>>(w1, w1T, Dn, DFn, flag);
    transpose_k<<<dim3(Dn / 32, DFn / 32), tb, 0, stream>>>(w2, w2T, DFn, Dn, flag);

    // LN1: x -> Rh
    ln_k<1><<<Mn / 8, 256, 0, stream>>>(x, g1, b1, Rh, flag);

    // fused QKV projection: [Mn][768] @ [768][2304] -> Rq|Rk|Rv (CSPLIT=768)
    gemm_bt<0, 0, 0, 64, Dn><<<dim3(Mn / 128, 3 * Dn / 128), 256, 0, stream>>>(
        Rh, wqkvT, biasf, nullptr, Rq, Mn, 3 * Dn, Dn, 0, flag);

    // Vt = V^T per (b,h): Rv -> Rh (Rh dead after QKV)
    vtrans_k<<<dim3(HDn / 32, Nn / 32, Bn * Hn), tb, 0, stream>>>(Rv, Rh);

    // attention: (Rq, Rk, Vt=Rh, mask) -> Rq (in-place over Q)
    attn_mfma_k<<<dim3(Hn, Nn / 64, Bn), 256, 0, stream>>>(Rq, Rk, Rh, maskbuf, Rq);

    // outb = attn @ wo + bo + x -> Rv  (V dead after vtrans)
    gemm_bt<0, 2, 0, 64, 0><<<dim3(Mn / 128, Dn / 128), 256, 0, stream>>>(
        Rq, woT, biasf + 2304, x, Rv, Mn, Dn, Dn, 0, flag);

    // LN2: Rv -> Rh (Vt dead after attn)
    ln_k<0><<<Mn / 8, 256, 0, stream>>>(Rv, g2, b2, Rh, flag);

    // FFN in 2 M-chunks of 8192; hidden (50.3 MB) spans Rq+Rk
    u16* hidden = Rq;
    for (int c = 0; c < Mn / MCHUNK; c++) {
        gemm_bt<1, 0, 0, 64, 0><<<dim3(MCHUNK / 128, DFn / 128), 256, 0, stream>>>(
            Rh + (size_t)c * MCHUNK * Dn, w1T, biasf + 3072, nullptr, hidden,
            MCHUNK, DFn, Dn, 0, flag);
        gemm_bt<0, 1, 1, 64, 0><<<dim3(MCHUNK / 128, Dn / 128), 256, 0, stream>>>(
            hidden, w2T, biasf + 6144, Rv, d_out, MCHUNK, Dn, DFn, c * MCHUNK, flag);
    }
}

// Round 4
// 645.022 us; speedup vs baseline: 1.0688x; 1.0688x over previous
//
#include <hip/hip_runtime.h>

// ---------------------------------------------------------------------------
// DenseGATLayer: LN1 -> fused QKV proj -> adj-masked MHA -> WO proj + residual
//                -> LN2 -> GELU FFN -> residual
// B=32 N=512 D=768 H=12 HD=64. bf16 MFMA, fp32 accumulation.
// R6: double-buffered single-barrier GEMM K-loop, 128x128 tiles, fused QKV.
// R7: parallel sniff_k (was 120us serial-latency).
// R8 POST-MORTEM: regressed (111->119us): exp2f() is libm-slow (not
// v_exp_f32) and +16 VGPR cut occupancy. R9: swapped-operand QK^T
// (mfma(K,Q) -> S^T: lane owns ONE q-row x 16 keys) -> 1 m/l chain per lane
// (was 4), in-lane row reduce (+2 shfl, was 16), fma-folded scale, no exp
// guard (scaled-domain m, init 0), __builtin_amdgcn_exp2f, cvt_pk_bf16 +
// ds_write_b64 P path (was 16 scalar b16 writes = bank conflicts).
// ---------------------------------------------------------------------------

#define Bn 32
#define Nn 512
#define Dn 768
#define Hn 12
#define HDn 64
#define Mn (Bn * Nn)      // 16384 rows
#define DFn 3072          // FFN hidden
#define MCHUNK 8192       // FFN M-chunk rows (hidden = 50.3 MB -> Rq+Rk)

typedef unsigned short u16;
typedef unsigned int u32;
typedef unsigned long long u64;
typedef short bf16x8 __attribute__((ext_vector_type(8)));
typedef float f32x4 __attribute__((ext_vector_type(4)));
typedef unsigned short u16x8 __attribute__((ext_vector_type(8)));
typedef unsigned int u32x2 __attribute__((ext_vector_type(2)));

__device__ __forceinline__ float b2f(u16 u) {
    return __uint_as_float(((unsigned int)u) << 16);
}
__device__ __forceinline__ u16 f2b(float f) {
    unsigned int u = __float_as_uint(f);
    u += 0x7fffu + ((u >> 16) & 1u);   // RNE
    return (u16)(u >> 16);
}
__device__ __forceinline__ float loadDyn(const void* p, size_t i, int f) {
    return f ? ((const float*)p)[i] : b2f(((const u16*)p)[i]);
}
__device__ __forceinline__ float gelu_exact(float x) {
    return 0.5f * x * (1.0f + erff(x * 0.70710678118654752f));
}

#if __has_builtin(__builtin_amdgcn_exp2f)
#define EXP2F(x) __builtin_amdgcn_exp2f(x)
#else
#define EXP2F(x) __expf((x) * 0.6931471805599453f)
#endif

// pack two f32 -> bf16x2 in one VALU op (no builtin on gfx950; m240)
__device__ __forceinline__ u32 pk_bf16(float lo, float hi) {
    u32 r;
    asm("v_cvt_pk_bf16_f32 %0, %1, %2" : "=v"(r) : "v"(lo), "v"(hi));
    return r;
}

// async global->LDS, 16B/lane; LDS dest = wave-uniform base + lane*16.
__device__ __forceinline__ void gl_lds16(const u16* g, u16* l) {
    __builtin_amdgcn_global_load_lds(
        (const __attribute__((address_space(1))) void*)(unsigned long long)(const void*)g,
        (__attribute__((address_space(3))) void*)(unsigned)(unsigned long long)(void*)l,
        16, 0, 0);
}

// ---------------------------------------------------------------------------
// Dtype sniffer (bf16 vs fp32 inputs). Parallel: 64 blocks x 256 threads x
// u16x8, wave-reduce, one atomicAdd per wave. flag pre-zeroed by
// hipMemsetAsync; consumers treat f = (*flag > 32).
// ---------------------------------------------------------------------------
__global__ __launch_bounds__(256) void sniff_k(const u16* __restrict__ x,
                                               int* __restrict__ flag) {
    const int idx = blockIdx.x * 256 + threadIdx.x;
    u16x8 a = *(const u16x8*)&x[(size_t)idx * 8];
    int cnt = 0;
#pragma unroll
    for (int e = 0; e < 8; e++)
        cnt += ((a[e] & 0x7F80) == 0x7F80) ? 1 : 0;
#pragma unroll
    for (int off = 1; off <= 32; off <<= 1) cnt += __shfl_xor(cnt, off, 64);
    if ((threadIdx.x & 63) == 0 && cnt > 0) atomicAdd(flag, cnt);
}

__device__ __forceinline__ int flagval(const int* flagp) {
    return (*flagp > 32) ? 1 : 0;
}

// ---------------------------------------------------------------------------
// Pack all bias vectors to fp32: [bq 768 | bk 768 | bv 768 | bo 768 |
// bf1 3072 | bf2 768] = 6912 floats.
// ---------------------------------------------------------------------------
__global__ __launch_bounds__(256) void pack_bias_k(
    const void* __restrict__ bq, const void* __restrict__ bk,
    const void* __restrict__ bv, const void* __restrict__ bo,
    const void* __restrict__ bf1, const void* __restrict__ bf2,
    float* __restrict__ out, const int* __restrict__ flagp) {
    const int f = flagval(flagp);
    const int i = blockIdx.x * 256 + threadIdx.x;
    if (i >= 6912) return;
    const void* src;
    int off;
    if (i < 768)       { src = bq;  off = i; }
    else if (i < 1536) { src = bk;  off = i - 768; }
    else if (i < 2304) { src = bv;  off = i - 1536; }
    else if (i < 3072) { src = bo;  off = i - 2304; }
    else if (i < 6144) { src = bf1; off = i - 3072; }
    else               { src = bf2; off = i - 6144; }
    out[i] = loadDyn(src, off, f);
}

// ---------------------------------------------------------------------------
// adj -> bitmask: mask[row*8 + seg] bit j = (adj[row][seg*64+j] != 0).
// ---------------------------------------------------------------------------
__global__ __launch_bounds__(256) void mask_build_k(
    const int* __restrict__ adj, u64* __restrict__ mask) {
    const int idx = blockIdx.x * 256 + threadIdx.x;   // Mn*8 = 131072 ids
    const size_t base = (size_t)(idx >> 3) * Nn + (size_t)(idx & 7) * 64;
    const int4* p = (const int4*)(adj + base);
    u64 m = 0;
#pragma unroll
    for (int c = 0; c < 16; c++) {
        int4 a = p[c];
        if (a.x) m |= 1ull << (c * 4 + 0);
        if (a.y) m |= 1ull << (c * 4 + 1);
        if (a.z) m |= 1ull << (c * 4 + 2);
        if (a.w) m |= 1ull << (c * 4 + 3);
    }
    mask[idx] = m;
}

// ---------------------------------------------------------------------------
// Transpose raw weight -> canonical bf16: out[c][r] = in[r][c]
// ---------------------------------------------------------------------------
__global__ __launch_bounds__(256) void transpose_k(
    const void* __restrict__ in, u16* __restrict__ out, int R, int C,
    const int* __restrict__ flagp) {
    const int f = flagval(flagp);
    __shared__ u16 tile[32][33];
    int c0 = blockIdx.x * 32, r0 = blockIdx.y * 32;
    int tx = threadIdx.x, ty = threadIdx.y;  // 32 x 8
#pragma unroll
    for (int i = 0; i < 32; i += 8)
        tile[ty + i][tx] = f2b(loadDyn(in, (size_t)(r0 + ty + i) * C + c0 + tx, f));
    __syncthreads();
#pragma unroll
    for (int i = 0; i < 32; i += 8)
        out[(size_t)(c0 + ty + i) * R + r0 + tx] = tile[tx][ty + i];
}

// ---------------------------------------------------------------------------
// V [b][n][h][d] -> Vt [b*H+h][d][n]
// ---------------------------------------------------------------------------
__global__ __launch_bounds__(256) void vtrans_k(
    const u16* __restrict__ v, u16* __restrict__ vt) {
    __shared__ u16 tile[32][33];
    const int bh = blockIdx.z;                 // b*Hn + h
    const int d0 = blockIdx.x * 32;            // 0 / 32
    const int n0 = blockIdx.y * 32;
    const int b = bh / Hn, h = bh % Hn;
    const int tx = threadIdx.x, ty = threadIdx.y;   // 32 x 8
#pragma unroll
    for (int i = 0; i < 32; i += 8)
        tile[ty + i][tx] =
            v[(size_t)(b * Nn + n0 + ty + i) * Dn + h * HDn + d0 + tx];
    __syncthreads();
#pragma unroll
    for (int i = 0; i < 32; i += 8)
        vt[((size_t)bh * HDn + d0 + ty + i) * Nn + n0 + tx] = tile[tx][ty + i];
}

// ---------------------------------------------------------------------------
// LayerNorm over D=768. 8 rows/block, 32 lanes/row, u16x8 vector loads.
// ---------------------------------------------------------------------------
template <int XDYN>
__global__ __launch_bounds__(256) void ln_k(
    const void* __restrict__ x, const void* __restrict__ g,
    const void* __restrict__ b, u16* __restrict__ y,
    const int* __restrict__ flagp) {
    const int f = flagval(flagp);
    const int t = threadIdx.x;
    const int row = blockIdx.x * 8 + (t >> 5);
    const int l32 = t & 31;
    const size_t base = (size_t)row * Dn;
    float v[24];
    if (XDYN == 0 || f == 0) {   // bf16 path (ws buffers always bf16)
        const u16* xp = (const u16*)x;
#pragma unroll
        for (int kk = 0; kk < 3; kk++) {
            u16x8 a = *(const u16x8*)&xp[base + kk * 256 + l32 * 8];
#pragma unroll
            for (int e = 0; e < 8; e++) v[kk * 8 + e] = b2f(a[e]);
        }
    } else {
#pragma unroll
        for (int kk = 0; kk < 3; kk++)
#pragma unroll
            for (int e = 0; e < 8; e++)
                v[kk * 8 + e] = loadDyn(x, base + kk * 256 + l32 * 8 + e, f);
    }
    float s = 0.f;
#pragma unroll
    for (int i = 0; i < 24; i++) s += v[i];
#pragma unroll
    for (int off = 1; off <= 16; off <<= 1) s += __shfl_xor(s, off, 64);
    const float mu = s * (1.0f / Dn);
    float d2 = 0.f;
#pragma unroll
    for (int i = 0; i < 24; i++) { float d = v[i] - mu; d2 += d * d; }
#pragma unroll
    for (int off = 1; off <= 16; off <<= 1) d2 += __shfl_xor(d2, off, 64);
    const float rstd = rsqrtf(d2 * (1.0f / Dn) + 1e-5f);
#pragma unroll
    for (int kk = 0; kk < 3; kk++) {
        const int c0 = kk * 256 + l32 * 8;
        u16x8 o;
        if (f == 0) {
            u16x8 gv = *(const u16x8*)&((const u16*)g)[c0];
            u16x8 bv = *(const u16x8*)&((const u16*)b)[c0];
#pragma unroll
            for (int e = 0; e < 8; e++)
                o[e] = f2b((v[kk * 8 + e] - mu) * rstd * b2f(gv[e]) + b2f(bv[e]));
        } else {
#pragma unroll
            for (int e = 0; e < 8; e++)
                o[e] = f2b((v[kk * 8 + e] - mu) * rstd * loadDyn(g, c0 + e, f)
                           + loadDyn(b, c0 + e, f));
        }
        *(u16x8*)&y[base + c0] = o;
    }
}

// ---------------------------------------------------------------------------
// GEMM: C[moff+M][N] = epi( A[M][K] @ Bt[N][K]^T + bias (+res) ).
// Block tile 128 x (2*WN), BK=32, 4 waves (2x2); wave tile 64 x WN.
// Double-buffered LDS, ONE barrier per K-step (stage-next-then-compute).
// CSPLIT>0: output columns routed in CSPLIT-wide regions to consecutive
// [M][CSPLIT] buffers (fused QKV -> contiguous Rq/Rk/Rv).
// ---------------------------------------------------------------------------
template <int ACT, int RES, int STORE, int WN, int CSPLIT>
__global__ __launch_bounds__(256, 3) void gemm_bt(
    const u16* __restrict__ A, const u16* __restrict__ Bt,
    const float* __restrict__ bias, const void* __restrict__ res,
    void* __restrict__ C, int M, int N, int K, int moff,
    const int* __restrict__ flagp) {
    constexpr int BN = 2 * WN;
    constexpr int NJ = WN / 16;       // B-fragments per wave
    constexpr int NB = BN / 64;       // B staging chunks per thread
    const int f = flagval(flagp);
    __shared__ __align__(16) u16 As[2][128 * 32];
    __shared__ __align__(16) u16 Bs[2][BN * 32];
    const int tid = threadIdx.x;
    const int m0 = blockIdx.x * 128, n0 = blockIdx.y * BN;
    const int wave = tid >> 6, lane = tid & 63;
    const int wm = (wave & 1) * 64, wn = (wave >> 1) * WN;
    const int lm = lane & 15, quad = lane >> 4;

    const int koff = (tid & 3) * 8;
    const int srow = tid >> 2;                       // 0..63
    const u16* gA[2];
    const u16* gB[NB];
#pragma unroll
    for (int i = 0; i < 2; i++)
        gA[i] = A + (size_t)(m0 + srow + i * 64) * K + koff;
#pragma unroll
    for (int i = 0; i < NB; i++)
        gB[i] = Bt + (size_t)(n0 + srow + i * 64) * K + koff;

    f32x4 acc[4][NJ] = {};

    auto stage = [&](int buf) {
#pragma unroll
        for (int i = 0; i < 2; i++) {
            gl_lds16(gA[i], &As[buf][(tid + i * 256) * 8]);
            gA[i] += 32;
        }
#pragma unroll
        for (int i = 0; i < NB; i++) {
            gl_lds16(gB[i], &Bs[buf][(tid + i * 256) * 8]);
            gB[i] += 32;
        }
    };
    auto compute = [&](int buf) {
        bf16x8 af[4], bfv[NJ];
#pragma unroll
        for (int i = 0; i < 4; i++)
            af[i] = *(const bf16x8*)&As[buf][(wm + i * 16 + lm) * 32 + quad * 8];
#pragma unroll
        for (int j = 0; j < NJ; j++)
            bfv[j] = *(const bf16x8*)&Bs[buf][(wn + j * 16 + lm) * 32 + quad * 8];
#pragma unroll
        for (int i = 0; i < 4; i++)
#pragma unroll
            for (int j = 0; j < NJ; j++)
                acc[i][j] = __builtin_amdgcn_mfma_f32_16x16x32_bf16(
                    af[i], bfv[j], acc[i][j], 0, 0, 0);
    };

    stage(0);                          // prologue: tile 0 in flight
    int cur = 0;
    for (int k0 = 32; k0 < K; k0 += 32) {
        __syncthreads();               // drains vmcnt: buf[cur] ready; prior
                                       // readers of buf[cur^1] are done
        stage(cur ^ 1);                // next tile flies during compute
        compute(cur);
        cur ^= 1;
    }
    __syncthreads();
    compute(cur);                      // epilogue tile (no prefetch)

    float bias_f[NJ];
#pragma unroll
    for (int j = 0; j < NJ; j++)
        bias_f[j] = bias[n0 + wn + j * 16 + lm];
#pragma unroll
    for (int i = 0; i < 4; i++) {
#pragma unroll
        for (int r = 0; r < 4; r++) {
            const int row = m0 + wm + i * 16 + quad * 4 + r;  // C/D: row=quad*4+reg
#pragma unroll
            for (int j = 0; j < NJ; j++) {
                int col = n0 + wn + j * 16 + lm;              // C/D: col=lane&15
                size_t rb;
                if (CSPLIT > 0) {
                    const int reg = col / CSPLIT;             // const div
                    rb = ((size_t)reg * M + moff + row) * (size_t)CSPLIT;
                    col -= reg * CSPLIT;
                } else {
                    rb = (size_t)(moff + row) * N;
                }
                float vv = acc[i][j][r] + bias_f[j];
                if (ACT == 1) vv = gelu_exact(vv);
                if (RES == 1) vv += b2f(((const u16*)res)[rb + col]);
                if (RES == 2) vv += loadDyn(res, rb + col, f);
                if (STORE == 0) ((u16*)C)[rb + col] = f2b(vv);
                else {
                    if (f) ((float*)C)[rb + col] = vv;
                    else   ((u16*)C)[rb + col] = f2b(vv);
                }
            }
        }
    }
}

// ---------------------------------------------------------------------------
// MFMA masked flash-attention, SWAPPED-OPERAND layout. Block = (h, q-tile 64,
// b), 4 waves; wave w owns q rows w*16..+16. QK^T computed as mfma(K,Q) ->
// S^T: lane (lm,quad) holds q-row (wm+lm), keys {j*16+quad*4+r}. Softmax is
// lane-local (1 m/l chain) + 2 shfl for the cross-quad reduce. m tracked in
// exp2-scaled domain, init 0 (self-loops guarantee each q-row has >=1 edge
// overall; masked-out -3e38 -> exp2 -> 0 exactly, no guard needed; all-masked
// tiles give p=0, alpha=1). P^T packed via v_cvt_pk_bf16_f32 (4 consecutive
// keys/reg) -> 4x ds_write_b64 to wave-private PsT rows (no barrier needed).
// PV: O^T = mfma(Vt_frag, PsT_frag) -- same ds_read_b128 addresses as before.
// K/Vt reg-prefetched one tile ahead (T14). o may alias q (block-private).
// ---------------------------------------------------------------------------
__global__ __launch_bounds__(256, 4) void attn_mfma_k(
    const u16* q, const u16* __restrict__ k,
    const u16* __restrict__ vt, const u64* __restrict__ mask, u16* o) {
    const int h = blockIdx.x, qg = blockIdx.y, b = blockIdx.z;
    const int q0 = qg * 64;
    const int tid = threadIdx.x;
    const int wave = tid >> 6, lane = tid & 63;
    const int lm = lane & 15, quad = lane >> 4;
    const int wm = wave * 16;
    const int bh = b * Hn + h;
    const float SC2 = 0.125f * 1.4426950408889634f;   // scale * log2(e)

    __shared__ __align__(16) u16 Ks[64 * 72];    // [key][dim]
    __shared__ __align__(16) u16 Vts[64 * 72];   // [dim][key]
    __shared__ __align__(16) u16 PsT[64 * 72];   // [q][key] (wave-private rows)

    // Q B-fragments: lane holds q-row (wm+lm), d-slices quad*8 (+32)
    const u16* qrow = q + ((size_t)(b * Nn + q0 + wm + lm)) * Dn + h * HDn + quad * 8;
    const bf16x8 aq0 = *(const bf16x8*)(qrow);
    const bf16x8 aq1 = *(const bf16x8*)(qrow + 32);

    // staging: thread stages K row srow / Vt dim srow, 32B chunk scc
    const int srow = tid >> 2, scc = (tid & 3) * 16;
    const u16* kbase = k + ((size_t)(b * Nn + srow)) * Dn + h * HDn + scc;
    const u16* vbase = vt + ((size_t)bh * HDn + srow) * Nn + scc;

    // prologue prefetch: tile kb=0 into regs
    u16x8 kr0 = *(const u16x8*)(kbase);
    u16x8 kr1 = *(const u16x8*)(kbase + 8);
    u16x8 vr0 = *(const u16x8*)(vbase);
    u16x8 vr1 = *(const u16x8*)(vbase + 8);

    float msc = 0.f, l_p = 0.f;     // scaled-domain running max, partial l
    f32x4 Oacc[4] = {};             // O^T: dim j*16+quad*4+r, q=lm

    for (int kb = 0; kb < Nn / 64; kb++) {
        __syncthreads();   // all waves done reading previous tile's Ks/Vts
        *(u16x8*)&Ks[srow * 72 + scc]      = kr0;
        *(u16x8*)&Ks[srow * 72 + scc + 8]  = kr1;
        *(u16x8*)&Vts[srow * 72 + scc]     = vr0;
        *(u16x8*)&Vts[srow * 72 + scc + 8] = vr1;
        __syncthreads();   // tile kb visible
        if (kb + 1 < Nn / 64) {      // T14: prefetch kb+1; latency hides below
            const u16* kn = kbase + (size_t)(kb + 1) * 64 * Dn;
            const u16* vn = vbase + (kb + 1) * 64;
            kr0 = *(const u16x8*)(kn);
            kr1 = *(const u16x8*)(kn + 8);
            vr0 = *(const u16x8*)(vn);
            vr1 = *(const u16x8*)(vn + 8);
        }
        // S^T = K Q^T: sacc[j] rows = keys j*16+quad*4+r, col = q (lm)
        f32x4 sacc[4] = {};
        __builtin_amdgcn_s_setprio(1);
#pragma unroll
        for (int s = 0; s < 2; s++) {
            const bf16x8 aq = s == 0 ? aq0 : aq1;
#pragma unroll
            for (int j = 0; j < 4; j++) {
                bf16x8 ak = *(const bf16x8*)&Ks[(j * 16 + lm) * 72 + s * 32 + quad * 8];
                sacc[j] = __builtin_amdgcn_mfma_f32_16x16x32_bf16(ak, aq, sacc[j], 0, 0, 0);
            }
        }
        __builtin_amdgcn_s_setprio(0);
        // mask: one u64 row per lane; pre-shift halves by quad*4 once
        const u64 mrow = mask[(size_t)(b * Nn + q0 + wm + lm) * 8 + kb];
        const u32 wlo = ((u32)mrow) >> (quad * 4);
        const u32 whi = ((u32)(mrow >> 32)) >> (quad * 4);
#pragma unroll
        for (int j = 0; j < 4; j++) {
            const u32 w = (j < 2) ? wlo : whi;
            const int sh = (j & 1) * 16;
#pragma unroll
            for (int r = 0; r < 4; r++)
                sacc[j][r] = ((w >> (sh + r)) & 1u) ? sacc[j][r] : -3e38f;
        }
        // in-lane row max over 16 keys + cross-quad reduce
        float mx = fmaxf(fmaxf(sacc[0][0], sacc[0][1]), fmaxf(sacc[0][2], sacc[0][3]));
#pragma unroll
        for (int j = 1; j < 4; j++)
            mx = fmaxf(mx, fmaxf(fmaxf(sacc[j][0], sacc[j][1]),
                                 fmaxf(sacc[j][2], sacc[j][3])));
        mx = fmaxf(mx, __shfl_xor(mx, 16, 64));
        mx = fmaxf(mx, __shfl_xor(mx, 32, 64));
        const float mn = fmaxf(msc, mx * SC2);
        const float alpha = EXP2F(msc - mn);
        msc = mn;
        // p = exp2(sc*SC2 - mn); masked (-3e38) -> arg ~ -5e37 -> 0 exactly
        float sum = 0.f;
#pragma unroll
        for (int j = 0; j < 4; j++)
#pragma unroll
            for (int r = 0; r < 4; r++) {
                const float p = EXP2F(fmaf(sacc[j][r], SC2, -mn));
                sacc[j][r] = p;
                sum += p;
            }
        l_p = l_p * alpha + sum;    // per-lane partial; cross-quad at end
#pragma unroll
        for (int j = 0; j < 4; j++)
#pragma unroll
            for (int r = 0; r < 4; r++) Oacc[j][r] *= alpha;
        // P^T -> PsT[q][key]: 4 consecutive keys per reg -> cvt_pk + b64
        {
            u16* prow = &PsT[(wm + lm) * 72];
#pragma unroll
            for (int j = 0; j < 4; j++) {
                u32x2 pk;
                pk.x = pk_bf16(sacc[j][0], sacc[j][1]);
                pk.y = pk_bf16(sacc[j][2], sacc[j][3]);
                *(u32x2*)&prow[j * 16 + quad * 4] = pk;
            }
        }
        // O^T += Vt P^T (A = Vt[dim][key], B = PsT rows: wave-private, same
        // wave wrote them -> lgkmcnt ordering only, no barrier)
        __builtin_amdgcn_s_setprio(1);
#pragma unroll
        for (int s = 0; s < 2; s++) {
            bf16x8 bp = *(const bf16x8*)&PsT[(wm + lm) * 72 + s * 32 + quad * 8];
#pragma unroll
            for (int j = 0; j < 4; j++) {
                bf16x8 av = *(const bf16x8*)&Vts[(j * 16 + lm) * 72 + s * 32 + quad * 8];
                Oacc[j] = __builtin_amdgcn_mfma_f32_16x16x32_bf16(av, bp, Oacc[j], 0, 0, 0);
            }
        }
        __builtin_amdgcn_s_setprio(0);
    }
    // l: reduce across the 4 quads sharing q-row lm
    float l = l_p;
    l += __shfl_xor(l, 16, 64);
    l += __shfl_xor(l, 32, 64);
    const float inv = (l > 0.f) ? 1.0f / l : 0.f;
    // store O[q][dim]: lane owns q-row wm+lm, dims j*16+quad*4+r
    u16* dst = o + ((size_t)(b * Nn + q0 + wm + lm)) * Dn + h * HDn;
#pragma unroll
    for (int j = 0; j < 4; j++) {
        u32x2 pk;
        pk.x = pk_bf16(Oacc[j][0] * inv, Oacc[j][1] * inv);
        pk.y = pk_bf16(Oacc[j][2] * inv, Oacc[j][3] * inv);
        *(u32x2*)&dst[j * 16 + quad * 4] = pk;
    }
}

// ---------------------------------------------------------------------------
extern "C" void kernel_launch(void* const* d_in, const int* in_sizes, int n_in,
                              void* d_out, int out_size, void* d_ws,
                              size_t ws_size, hipStream_t stream) {
    const void* x   = d_in[0];
    const int* adj  = (const int*)d_in[1];
    const void* wq  = d_in[2];
    const void* bq  = d_in[3];
    const void* wk  = d_in[4];
    const void* bk  = d_in[5];
    const void* wv  = d_in[6];
    const void* bv  = d_in[7];
    const void* wo  = d_in[8];
    const void* bo  = d_in[9];
    const void* g1  = d_in[10];
    const void* b1  = d_in[11];
    const void* g2  = d_in[12];
    const void* b2  = d_in[13];
    const void* w1  = d_in[14];
    const void* bf1 = d_in[15];
    const void* w2  = d_in[16];
    const void* bf2 = d_in[17];

    // ---- workspace (~116 MiB) ----
    char* ws = (char*)d_ws;
    size_t off = 0;
    auto alloc = [&](size_t bytes) -> char* {
        char* p = ws + off;
        off += (bytes + 255) & ~(size_t)255;
        return p;
    };
    int* flag = (int*)alloc(4);
    u16* wqkvT = (u16*)alloc((size_t)3 * Dn * Dn * 2);     // [2304][768]
    u16* woT  = (u16*)alloc((size_t)Dn * Dn * 2);
    u16* w1T  = (u16*)alloc((size_t)Dn * DFn * 2);
    u16* w2T  = (u16*)alloc((size_t)Dn * DFn * 2);
    float* biasf = (float*)alloc(6912 * 4);                // packed fp32 biases
    u64* maskbuf = (u64*)alloc((size_t)Mn * 8 * 8);        // 1 MB
    const size_t S = (size_t)Mn * Dn * 2;                  // 25.17 MB (256-mult)
    u16* Rh = (u16*)alloc(S);   // LN1-h -> Vt -> LN2-h2
    u16* Rq = (u16*)alloc(S);   // Q -> attn-out -> hidden[lo]
    u16* Rk = (u16*)alloc(S);   // K -> hidden[hi]  (Rq+S == Rk: contiguous)
    u16* Rv = (u16*)alloc(S);   // V -> outb (WO out + residual)  (Rk+S == Rv)

    hipMemsetAsync(flag, 0, 4, stream);
    sniff_k<<<64, 256, 0, stream>>>((const u16*)x, flag);
    mask_build_k<<<Mn * 8 / 256, 256, 0, stream>>>(adj, maskbuf);
    pack_bias_k<<<27, 256, 0, stream>>>(bq, bk, bv, bo, bf1, bf2, biasf, flag);

    dim3 tb(32, 8);
    // fused QKV weight: rows 0..767 = wq^T, 768..1535 = wk^T, 1536..2303 = wv^T
    transpose_k<<<dim3(Dn / 32, Dn / 32), tb, 0, stream>>>(wq, wqkvT, Dn, Dn, flag);
    transpose_k<<<dim3(Dn / 32, Dn / 32), tb, 0, stream>>>(wk, wqkvT + (size_t)Dn * Dn, Dn, Dn, flag);
    transpose_k<<<dim3(Dn / 32, Dn / 32), tb, 0, stream>>>(wv, wqkvT + (size_t)2 * Dn * Dn, Dn, Dn, flag);
    transpose_k<<<dim3(Dn / 32, Dn / 32), tb, 0, stream>>>(wo, woT, Dn, Dn, flag);
    transpose_k<<<dim3(DFn / 32, Dn / 32), tb, 0, stream>>>(w1, w1T, Dn, DFn, flag);
    transpose_k<<<dim3(Dn / 32, DFn / 32), tb, 0, stream>>>(w2, w2T, DFn, Dn, flag);

    // LN1: x -> Rh
    ln_k<1><<<Mn / 8, 256, 0, stream>>>(x, g1, b1, Rh, flag);

    // fused QKV projection: [Mn][768] @ [768][2304] -> Rq|Rk|Rv (CSPLIT=768)
    gemm_bt<0, 0, 0, 64, Dn><<<dim3(Mn / 128, 3 * Dn / 128), 256, 0, stream>>>(
        Rh, wqkvT, biasf, nullptr, Rq, Mn, 3 * Dn, Dn, 0, flag);

    // Vt = V^T per (b,h): Rv -> Rh (Rh dead after QKV)
    vtrans_k<<<dim3(HDn / 32, Nn / 32, Bn * Hn), tb, 0, stream>>>(Rv, Rh);

    // attention: (Rq, Rk, Vt=Rh, mask) -> Rq (in-place over Q)
    attn_mfma_k<<<dim3(Hn, Nn / 64, Bn), 256, 0, stream>>>(Rq, Rk, Rh, maskbuf, Rq);

    // outb = attn @ wo + bo + x -> Rv  (V dead after vtrans)
    gemm_bt<0, 2, 0, 64, 0><<<dim3(Mn / 128, Dn / 128), 256, 0, stream>>>(
        Rq, woT, biasf + 2304, x, Rv, Mn, Dn, Dn, 0, flag);

    // LN2: Rv -> Rh (Vt dead after attn)
    ln_k<0><<<Mn / 8, 256, 0, stream>>>(Rv, g2, b2, Rh, flag);

    // FFN in 2 M-chunks of 8192; hidden (50.3 MB) spans Rq+Rk
    u16* hidden = Rq;
    for (int c = 0; c < Mn / MCHUNK; c++) {
        gemm_bt<1, 0, 0, 64, 0><<<dim3(MCHUNK / 128, DFn / 128), 256, 0, stream>>>(
            Rh + (size_t)c * MCHUNK * Dn, w1T, biasf + 3072, nullptr, hidden,
            MCHUNK, DFn, Dn, 0, flag);
        gemm_bt<0, 1, 1, 64, 0><<<dim3(MCHUNK / 128, Dn / 128), 256, 0, stream>>>(
            hidden, w2T, biasf + 6144, Rv, d_out, MCHUNK, Dn, DFn, c * MCHUNK, flag);
    }
}